// Round 10
// baseline (368.710 us; speedup 1.0000x reference)
//
#include <hip/hip_runtime.h>
#include <hip/hip_fp16.h>
#include <stdint.h>

#define NP 100000
#define KA 3.2188758248682006f   // -2*ln(0.2)
#define KB 0.44628710262841953f  // -2*ln(0.8)
#define PSCALE 16.0f             // planes stored *16 in e4m3; folded out at epilogue

// workspace layout in DWORDS: planes as [H][W][8 dwords] fp8 (32 feats * 1B),
// then sample records float4 [13][NP]
#define SS_DW 131072    // 128*128*8
#define ST_DW 102400    // 128*100*8
#define OFF0 0
#define OFF1 (OFF0 + SS_DW)
#define OFF2 (OFF1 + SS_DW)
#define OFF3 (OFF2 + ST_DW)
#define OFF4 (OFF3 + SS_DW)
#define OFF5 (OFF4 + ST_DW)
#define REC_OFF (OFF5 + ST_DW)   // 700416 dwords = 2801664 B (16B-aligned)

typedef float v2f __attribute__((ext_vector_type(2)));
typedef __fp16 v2h __attribute__((ext_vector_type(2)));

__device__ __forceinline__ int clampi(int v, int hi){ v = v < 0 ? 0 : v; return v > hi ? hi : v; }

struct Dim { int i0, i1; float fr; };

__device__ __forceinline__ Dim mkdim(float g, int hi){
  float fl = floorf(g);
  Dim d;
  d.fr = g - fl;            // unclipped fractional weight (faithful to reference)
  int i = (int)fl;
  d.i0 = clampi(i, hi);
  d.i1 = clampi(i + 1, hi);
  return d;
}

// decode 2 fp8 -> 2 f16 (direct HW path when available; else via f32).
template<bool HI>
__device__ __forceinline__ __half2 dec8(uint32_t w){
#if __has_builtin(__builtin_amdgcn_cvt_scalef32_pk_f16_fp8)
  v2h h = __builtin_amdgcn_cvt_scalef32_pk_f16_fp8(w, 1.0f, HI);
  return __builtin_bit_cast(__half2, h);
#else
  v2f f = __builtin_amdgcn_cvt_pk_f32_fp8((int)w, HI);
  v2h h = __builtin_amdgcn_cvt_pkrtz(f.x, f.y);
  return __builtin_bit_cast(__half2, h);
#endif
}

// decode 16 fp8 feats (uint4) and accumulate with packed-f16 weight
__device__ __forceinline__ void row8(uint4 v, __half2 w, __half2* acc){
  acc[0] = __hfma2(dec8<false>(v.x), w, acc[0]);
  acc[1] = __hfma2(dec8<true >(v.x), w, acc[1]);
  acc[2] = __hfma2(dec8<false>(v.y), w, acc[2]);
  acc[3] = __hfma2(dec8<true >(v.y), w, acc[3]);
  acc[4] = __hfma2(dec8<false>(v.z), w, acc[4]);
  acc[5] = __hfma2(dec8<true >(v.z), w, acc[5]);
  acc[6] = __hfma2(dec8<false>(v.w), w, acc[6]);
  acc[7] = __hfma2(dec8<true >(v.w), w, acc[7]);
}

// one plane, one sample: 2 loads of 16B/lane covering the 64B (x0,x1) span.
__device__ __forceinline__ void bilinpair(const uint4* __restrict__ P,
    int rA, int rB, int x0, __half2 wx, __half2 wyg, __half2 wyf,
    int fp, __half2* acc){
  uint4 vA = P[((rA + x0) << 1) + fp];
  uint4 vB = P[((rB + x0) << 1) + fp];
  __half2 wA = __hmul2(wyg, wx), wB = __hmul2(wyf, wx);
  row8(vA, wA, acc);
  row8(vB, wB, acc);
}

__device__ __forceinline__ float3 eigvec3(float c00,float c01,float c02,
                                          float c11,float c12,float c22,float lam){
  float m00 = c00 - lam, m11 = c11 - lam, m22 = c22 - lam;
  float ux0 = c01*c12 - c02*m11, uy0 = c02*c01 - m00*c12, uz0 = m00*m11 - c01*c01;
  float ux1 = c01*m22 - c02*c12, uy1 = c02*c02 - m00*m22, uz1 = m00*c12 - c01*c02;
  float ux2 = m11*m22 - c12*c12, uy2 = c12*c02 - c01*m22, uz2 = c01*c12 - m11*c02;
  float n0 = ux0*ux0 + uy0*uy0 + uz0*uz0;
  float n1 = ux1*ux1 + uy1*uy1 + uz1*uz1;
  float n2 = ux2*ux2 + uy2*uy2 + uz2*uz2;
  float ux = ux0, uy = uy0, uz = uz0, nn = n0;
  if (n1 > nn){ ux = ux1; uy = uy1; uz = uz1; nn = n1; }
  if (n2 > nn){ ux = ux2; uy = uy2; uz = uz2; nn = n2; }
  float inv = 1.0f / sqrtf(nn + 1e-45f);
  return make_float3(ux*inv, uy*inv, uz*inv);
}

// ---- transpose + quantize: [32][HW] f32 -> [HW][32] fp8 (*16), coalesced ----
__global__ __launch_bounds__(256) void wpf_transpose(
    const float* __restrict__ p0, const float* __restrict__ p1,
    const float* __restrict__ p2, const float* __restrict__ p3,
    const float* __restrict__ p4, const float* __restrict__ p5,
    uint32_t* __restrict__ ws, float* __restrict__ coltime)
{
  __shared__ float tile[32][65];
  int plane = blockIdx.y;
  if (plane == 0 && blockIdx.x == 0 && threadIdx.x == 0) coltime[0] = 1.0f;
  const float* src; int off, HW;
  switch (plane){
    case 0:  src = p0; off = OFF0; HW = 16384; break;
    case 1:  src = p1; off = OFF1; HW = 16384; break;
    case 2:  src = p2; off = OFF2; HW = 12800; break;
    case 3:  src = p3; off = OFF3; HW = 16384; break;
    case 4:  src = p4; off = OFF4; HW = 12800; break;
    default: src = p5; off = OFF5; HW = 12800; break;
  }
  int hw0 = blockIdx.x * 64;
  if (hw0 >= HW) return;
  int hwt = threadIdx.x & 63;
  int fq  = threadIdx.x >> 6;   // 0..3
  #pragma unroll
  for (int i = 0; i < 8; ++i){
    int f = fq * 8 + i;         // 0..31
    tile[f][hwt] = src[f * HW + hw0 + hwt];  // coalesced
  }
  __syncthreads();
  int d  = threadIdx.x & 7;     // dword index 0..7 (feats 4d..4d+3)
  int h2 = threadIdx.x >> 3;    // 0..31
  #pragma unroll
  for (int i = 0; i < 2; ++i){
    int hl = i * 32 + h2;       // 0..63
    float a = tile[4*d+0][hl] * PSCALE;
    float b = tile[4*d+1][hl] * PSCALE;
    float c = tile[4*d+2][hl] * PSCALE;
    float e = tile[4*d+3][hl] * PSCALE;
    int r = __builtin_amdgcn_cvt_pk_fp8_f32(a, b, 0, false);
    r     = __builtin_amdgcn_cvt_pk_fp8_f32(c, e, r, true);
    ws[off + (hw0 + hl) * 8 + d] = (uint32_t)r;   // coalesced 256B/wave
  }
}

// ---- geometry: 1 thread/point, writes 13 grid-space records [m][NP] ----
__global__ __launch_bounds__(256) void wpf_geom(
    const float* __restrict__ pts, const float* __restrict__ tim,
    const float* __restrict__ cov6, float4* __restrict__ rec)
{
  int pt = blockIdx.x * 256 + threadIdx.x;
  if (pt >= NP) return;

  float px = pts[pt*3+0], py = pts[pt*3+1], pz = pts[pt*3+2];
  float c00 = cov6[pt*6+0], c01 = cov6[pt*6+1], c02 = cov6[pt*6+2];
  float c11 = cov6[pt*6+3], c12 = cov6[pt*6+4], c22 = cov6[pt*6+5];

  // analytic symmetric 3x3 eigendecomposition, ascending eigenvalues
  float q3 = (c00 + c11 + c22) * (1.0f/3.0f);
  float p1 = c01*c01 + c02*c02 + c12*c12;
  float d00 = c00 - q3, d11 = c11 - q3, d22 = c22 - q3;
  float p2 = d00*d00 + d11*d11 + d22*d22 + 2.0f*p1;
  float pp = sqrtf(p2 * (1.0f/6.0f)) + 1e-30f;
  float pinv = 1.0f / pp;
  float b00 = d00*pinv, b11 = d11*pinv, b22 = d22*pinv;
  float b01 = c01*pinv, b02 = c02*pinv, b12 = c12*pinv;
  float detB = b00*(b11*b22 - b12*b12) - b01*(b01*b22 - b12*b02) + b02*(b01*b12 - b11*b02);
  float r = fminf(1.0f, fmaxf(-1.0f, 0.5f * detB));
  float phi = acosf(r) * (1.0f/3.0f);
  float l2 = q3 + 2.0f*pp*cosf(phi);                          // largest
  float l0 = q3 + 2.0f*pp*cosf(phi + 2.0943951023931953f);    // smallest
  float3 v0 = eigvec3(c00,c01,c02,c11,c12,c22, l0);
  float3 v2 = eigvec3(c00,c01,c02,c11,c12,c22, l2);
  float v1x = v2.y*v0.z - v2.z*v0.y;
  float v1y = v2.z*v0.x - v2.x*v0.z;
  float v1z = v2.x*v0.y - v2.y*v0.x;
  float v1inv = 1.0f / sqrtf(v1x*v1x + v1y*v1y + v1z*v1z + 1e-45f);
  v1x *= v1inv; v1y *= v1inv; v1z *= v1inv;

  float nx[3] = { v0.x, v0.y, v0.z };
  float ny[3] = { v1x,  v1y,  v1z  };
  float nz[3] = { v2.x, v2.y, v2.z };

  // Cinv via adjugate/det
  float A00 = c11*c22 - c12*c12;
  float A01 = c02*c12 - c01*c22;
  float A02 = c01*c12 - c02*c11;
  float A11 = c00*c22 - c02*c02;
  float A12 = c01*c02 - c00*c12;
  float A22 = c00*c11 - c01*c01;
  float det  = c00*A00 + c01*A01 + c02*A02;
  float dinv = 1.0f / det;
  float i00 = A00*dinv, i01 = A01*dinv, i02 = A02*dinv;
  float i11 = A11*dinv, i12 = A12*dinv, i22 = A22*dinv;

  // grid-space center and scaled offsets: grid = 63.5 - 39.6875*world
  float gpx = fmaf(px, -39.6875f, 63.5f);
  float gpy = fmaf(py, -39.6875f, 63.5f);
  float gpz = fmaf(pz, -39.6875f, 63.5f);
  float axA[3], ayA[3], azA[3], axB[3], ayB[3], azB[3];
  #pragma unroll
  for (int k = 0; k < 3; ++k){
    float a = nx[k], b = ny[k], c = nz[k];
    float lam = i00*a*a + i11*b*b + i22*c*c + 2.0f*(i01*a*b + i02*a*c + i12*b*c);
    float linv = 1.0f / lam;
    float sA = -39.6875f * sqrtf(KA * linv);
    float sB = -39.6875f * sqrtf(KB * linv);
    axA[k] = sA*a; ayA[k] = sA*b; azA[k] = sA*c;
    axB[k] = sB*a; ayB[k] = sB*b; azB[k] = sB*c;
  }

  // faithful to jnp.tile(t,(13,1)): sample m of point n uses time[(13n+m) % N]
  int tb = (pt * 13) % NP;
  int ti = tb;
  rec[0*NP + pt] = make_float4(gpx, gpy, gpz, tim[ti] * 99.0f);
  #pragma unroll
  for (int k = 0; k < 3; ++k){
    ti = tb + 1 + k; if (ti >= NP) ti -= NP;
    rec[(1+k)*NP + pt]  = make_float4(gpx+axA[k], gpy+ayA[k], gpz+azA[k], tim[ti]*99.0f);
  }
  #pragma unroll
  for (int k = 0; k < 3; ++k){
    ti = tb + 4 + k; if (ti >= NP) ti -= NP;
    rec[(4+k)*NP + pt]  = make_float4(gpx+axB[k], gpy+ayB[k], gpz+azB[k], tim[ti]*99.0f);
  }
  #pragma unroll
  for (int k = 0; k < 3; ++k){
    ti = tb + 7 + k; if (ti >= NP) ti -= NP;
    rec[(7+k)*NP + pt]  = make_float4(gpx-axA[k], gpy-ayA[k], gpz-azA[k], tim[ti]*99.0f);
  }
  #pragma unroll
  for (int k = 0; k < 3; ++k){
    ti = tb + 10 + k; if (ti >= NP) ti -= NP;
    rec[(10+k)*NP + pt] = make_float4(gpx-axB[k], gpy-ayB[k], gpz-azB[k], tim[ti]*99.0f);
  }
}

// ---- gather: 4 lanes/point, no LDS, no sync, max occupancy ----
__global__ __launch_bounds__(256, 8) void wpf_gather(
    const float4* __restrict__ rec, const uint32_t* __restrict__ ws,
    float* __restrict__ out)
{
  int tid = blockIdx.x * 256 + threadIdx.x;
  int pt = tid >> 2, fp = tid & 3;
  if (pt >= NP) return;
  bool xhi = (fp & 2) != 0;            // lanes 2,3 hold the x1 corner

  const uint4* __restrict__ w0p = reinterpret_cast<const uint4*>(ws + OFF0);
  const uint4* __restrict__ w1p = reinterpret_cast<const uint4*>(ws + OFF1);
  const uint4* __restrict__ w2p = reinterpret_cast<const uint4*>(ws + OFF2);
  const uint4* __restrict__ w3p = reinterpret_cast<const uint4*>(ws + OFF3);
  const uint4* __restrict__ w4p = reinterpret_cast<const uint4*>(ws + OFF4);
  const uint4* __restrict__ w5p = reinterpret_cast<const uint4*>(ws + OFF5);

  __half2 acc[6][8];                   // 16 feats/lane (this lane's x-corner partial)
  __half2 z = __float2half2_rn(0.0f);
  #pragma unroll
  for (int i = 0; i < 6; ++i)
    #pragma unroll
    for (int j = 0; j < 8; ++j) acc[i][j] = z;

  #pragma unroll 2
  for (int m = 0; m < 13; ++m){
    float4 s = rec[m*NP + pt];         // quad-broadcast 16B load
    Dim d0 = mkdim(s.x, 127);
    Dim d1 = mkdim(s.y, 127);
    Dim d2 = mkdim(s.z, 127);
    Dim dt = mkdim(s.w, 99);

    // x-use weights: zero the x1 weight when corners clamp to the same cell
    float f0x = (d0.i0 == d0.i1) ? 0.0f : d0.fr;
    float f1x = (d1.i0 == d1.i1) ? 0.0f : d1.fr;
    float ftx = (dt.i0 == dt.i1) ? 0.0f : dt.fr;

    __half2 f0h = __float2half2_rn(d0.fr), g0h = __float2half2_rn(1.0f - d0.fr);
    __half2 f1h = __float2half2_rn(d1.fr), g1h = __float2half2_rn(1.0f - d1.fr);
    __half2 f2h = __float2half2_rn(d2.fr), g2h = __float2half2_rn(1.0f - d2.fr);

    __half2 wx0 = __float2half2_rn(xhi ? f0x : 1.0f - f0x);
    __half2 wx1 = __float2half2_rn(xhi ? f1x : 1.0f - f1x);
    __half2 wxt = __float2half2_rn(xhi ? ftx : 1.0f - ftx);

    int r1a = d1.i0 << 7, r1b = d1.i1 << 7;   // y=s1, W=128 (plane0)
    int r2a = d2.i0 << 7, r2b = d2.i1 << 7;   // y=s2, W=128 (planes1,3)
    int q0a = d0.i0 * 100, q0b = d0.i1 * 100; // y=s0, W=100 (plane2)
    int q1a = d1.i0 * 100, q1b = d1.i1 * 100; // y=s1, W=100 (plane4)
    int q2a = d2.i0 * 100, q2b = d2.i1 * 100; // y=s2, W=100 (plane5)

    bilinpair(w0p, r1a, r1b, d0.i0, wx0, g1h, f1h, fp, acc[0]); // x=s0,y=s1
    bilinpair(w1p, r2a, r2b, d0.i0, wx0, g2h, f2h, fp, acc[1]); // x=s0,y=s2
    bilinpair(w2p, q0a, q0b, dt.i0, wxt, g0h, f0h, fp, acc[2]); // x=t, y=s0
    bilinpair(w3p, r2a, r2b, d1.i0, wx1, g2h, f2h, fp, acc[3]); // x=s1,y=s2
    bilinpair(w4p, q1a, q1b, dt.i0, wxt, g1h, f1h, fp, acc[4]); // x=t, y=s1
    bilinpair(w5p, q2a, q2b, dt.i0, wxt, g2h, f2h, fp, acc[5]); // x=t, y=s2
  }

  // combine x0/x1 partials across lane^2
  #pragma unroll
  for (int i = 0; i < 6; ++i)
    #pragma unroll
    for (int j = 0; j < 8; ++j){
      int o = __shfl_xor(__builtin_bit_cast(int, acc[i][j]), 2);
      acc[i][j] = __hadd2(acc[i][j], __builtin_bit_cast(__half2, o));
    }

  if (fp < 2){   // lanes 0,1 write feats 0-15 / 16-31 (lanes 2,3 are duplicates)
    const float s13 = 1.0f / (13.0f * PSCALE);
    float sp[16], st[16];
    #pragma unroll
    for (int j = 0; j < 8; ++j){
      float2 a0 = __half22float2(acc[0][j]);
      float2 a1 = __half22float2(acc[1][j]);
      float2 a2 = __half22float2(acc[2][j]);
      float2 a3 = __half22float2(acc[3][j]);
      float2 a4 = __half22float2(acc[4][j]);
      float2 a5 = __half22float2(acc[5][j]);
      sp[2*j]   = (a0.x*s13)*(a1.x*s13)*(a3.x*s13);
      sp[2*j+1] = (a0.y*s13)*(a1.y*s13)*(a3.y*s13);
      st[2*j]   = (a2.x*s13)*(a4.x*s13)*(a5.x*s13);
      st[2*j+1] = (a2.y*s13)*(a4.y*s13)*(a5.y*s13);
    }
    float* osp = out + pt*32 + fp*16;
    float* ost = osp + NP*32;
    #pragma unroll
    for (int q = 0; q < 4; ++q){
      reinterpret_cast<float4*>(osp)[q] = make_float4(sp[4*q], sp[4*q+1], sp[4*q+2], sp[4*q+3]);
      reinterpret_cast<float4*>(ost)[q] = make_float4(st[4*q], st[4*q+1], st[4*q+2], st[4*q+3]);
    }
  }
}

extern "C" void kernel_launch(void* const* d_in, const int* in_sizes, int n_in,
                              void* d_out, int out_size, void* d_ws, size_t ws_size,
                              hipStream_t stream) {
  (void)in_sizes; (void)n_in; (void)out_size; (void)ws_size;
  const float* pts  = (const float*)d_in[0];
  const float* tim  = (const float*)d_in[1];
  const float* cov6 = (const float*)d_in[2];
  const float* p0 = (const float*)d_in[3];
  const float* p1 = (const float*)d_in[4];
  const float* p2 = (const float*)d_in[5];
  const float* p3 = (const float*)d_in[6];
  const float* p4 = (const float*)d_in[7];
  const float* p5 = (const float*)d_in[8];
  float* out = (float*)d_out;
  uint32_t* ws = (uint32_t*)d_ws;
  float4* rec = reinterpret_cast<float4*>(ws + REC_OFF);

  dim3 tgrid(256, 6);
  wpf_transpose<<<tgrid, 256, 0, stream>>>(p0, p1, p2, p3, p4, p5, ws, out + 2*NP*32);

  wpf_geom<<<(NP + 255) / 256, 256, 0, stream>>>(pts, tim, cov6, rec);

  int nthreads = NP * 4;
  wpf_gather<<<(nthreads + 255) / 256, 256, 0, stream>>>(rec, ws, out);
}

// Round 12
// 189.472 us; speedup vs baseline: 1.9460x; 1.9460x over previous
//
#include <hip/hip_runtime.h>
#include <hip/hip_fp16.h>
#include <stdint.h>

#define NP 100000
#define KA 3.2188758248682006f   // -2*ln(0.2)
#define KB 0.44628710262841953f  // -2*ln(0.8)
#define PSCALE 16.0f             // planes stored *16 in e4m3; folded out at epilogue

// workspace layout in DWORDS: planes as [H][W][8 dwords] fp8 (32 feats * 1B),
// then sample records float4 [13][NP]
#define SS_DW 131072    // 128*128*8
#define ST_DW 102400    // 128*100*8
#define OFF0 0
#define OFF1 (OFF0 + SS_DW)
#define OFF2 (OFF1 + SS_DW)
#define OFF3 (OFF2 + ST_DW)
#define OFF4 (OFF3 + SS_DW)
#define OFF5 (OFF4 + ST_DW)
#define REC_OFF (OFF5 + ST_DW)   // 700416 dwords = 2801664 B (16B-aligned)

typedef float v2f __attribute__((ext_vector_type(2)));
typedef __fp16 v2h __attribute__((ext_vector_type(2)));

__device__ __forceinline__ int clampi(int v, int hi){ v = v < 0 ? 0 : v; return v > hi ? hi : v; }

struct Dim { int i0, i1; float fr; };

__device__ __forceinline__ Dim mkdim(float g, int hi){
  float fl = floorf(g);
  Dim d;
  d.fr = g - fl;            // unclipped fractional weight (faithful to reference)
  int i = (int)fl;
  d.i0 = clampi(i, hi);
  d.i1 = clampi(i + 1, hi);
  return d;
}

// decode 2 fp8 -> 2 f16 (direct HW path when available; else via f32).
template<bool HI>
__device__ __forceinline__ __half2 dec8(uint32_t w){
#if __has_builtin(__builtin_amdgcn_cvt_scalef32_pk_f16_fp8)
  v2h h = __builtin_amdgcn_cvt_scalef32_pk_f16_fp8(w, 1.0f, HI);
  return __builtin_bit_cast(__half2, h);
#else
  v2f f = __builtin_amdgcn_cvt_pk_f32_fp8((int)w, HI);
  v2h h = __builtin_amdgcn_cvt_pkrtz(f.x, f.y);
  return __builtin_bit_cast(__half2, h);
#endif
}

// decode 16 fp8 feats (uint4) and accumulate with packed-f16 weight
__device__ __forceinline__ void row8(uint4 v, __half2 w, __half2* acc){
  acc[0] = __hfma2(dec8<false>(v.x), w, acc[0]);
  acc[1] = __hfma2(dec8<true >(v.x), w, acc[1]);
  acc[2] = __hfma2(dec8<false>(v.y), w, acc[2]);
  acc[3] = __hfma2(dec8<true >(v.y), w, acc[3]);
  acc[4] = __hfma2(dec8<false>(v.z), w, acc[4]);
  acc[5] = __hfma2(dec8<true >(v.z), w, acc[5]);
  acc[6] = __hfma2(dec8<false>(v.w), w, acc[6]);
  acc[7] = __hfma2(dec8<true >(v.w), w, acc[7]);
}

// one plane, one sample: 2 loads of 16B/lane covering the 64B (x0,x1) span.
__device__ __forceinline__ void bilinpair(const uint4* __restrict__ P,
    int rA, int rB, int x0, __half2 wx, __half2 wyg, __half2 wyf,
    int fp, __half2* acc){
  uint4 vA = P[((rA + x0) << 1) + fp];
  uint4 vB = P[((rB + x0) << 1) + fp];
  __half2 wA = __hmul2(wyg, wx), wB = __hmul2(wyf, wx);
  row8(vA, wA, acc);
  row8(vB, wB, acc);
}

__device__ __forceinline__ float3 eigvec3(float c00,float c01,float c02,
                                          float c11,float c12,float c22,float lam){
  float m00 = c00 - lam, m11 = c11 - lam, m22 = c22 - lam;
  float ux0 = c01*c12 - c02*m11, uy0 = c02*c01 - m00*c12, uz0 = m00*m11 - c01*c01;
  float ux1 = c01*m22 - c02*c12, uy1 = c02*c02 - m00*m22, uz1 = m00*c12 - c01*c02;
  float ux2 = m11*m22 - c12*c12, uy2 = c12*c02 - c01*m22, uz2 = c01*c12 - m11*c02;
  float n0 = ux0*ux0 + uy0*uy0 + uz0*uz0;
  float n1 = ux1*ux1 + uy1*uy1 + uz1*uz1;
  float n2 = ux2*ux2 + uy2*uy2 + uz2*uz2;
  float ux = ux0, uy = uy0, uz = uz0, nn = n0;
  if (n1 > nn){ ux = ux1; uy = uy1; uz = uz1; nn = n1; }
  if (n2 > nn){ ux = ux2; uy = uy2; uz = uz2; nn = n2; }
  float inv = 1.0f / sqrtf(nn + 1e-45f);
  return make_float3(ux*inv, uy*inv, uz*inv);
}

// ---- transpose + quantize: [32][HW] f32 -> [HW][32] fp8 (*16), coalesced ----
__global__ __launch_bounds__(256) void wpf_transpose(
    const float* __restrict__ p0, const float* __restrict__ p1,
    const float* __restrict__ p2, const float* __restrict__ p3,
    const float* __restrict__ p4, const float* __restrict__ p5,
    uint32_t* __restrict__ ws, float* __restrict__ coltime)
{
  __shared__ float tile[32][65];
  int plane = blockIdx.y;
  if (plane == 0 && blockIdx.x == 0 && threadIdx.x == 0) coltime[0] = 1.0f;
  const float* src; int off, HW;
  switch (plane){
    case 0:  src = p0; off = OFF0; HW = 16384; break;
    case 1:  src = p1; off = OFF1; HW = 16384; break;
    case 2:  src = p2; off = OFF2; HW = 12800; break;
    case 3:  src = p3; off = OFF3; HW = 16384; break;
    case 4:  src = p4; off = OFF4; HW = 12800; break;
    default: src = p5; off = OFF5; HW = 12800; break;
  }
  int hw0 = blockIdx.x * 64;
  if (hw0 >= HW) return;
  int hwt = threadIdx.x & 63;
  int fq  = threadIdx.x >> 6;   // 0..3
  #pragma unroll
  for (int i = 0; i < 8; ++i){
    int f = fq * 8 + i;         // 0..31
    tile[f][hwt] = src[f * HW + hw0 + hwt];  // coalesced
  }
  __syncthreads();
  int d  = threadIdx.x & 7;     // dword index 0..7 (feats 4d..4d+3)
  int h2 = threadIdx.x >> 3;    // 0..31
  #pragma unroll
  for (int i = 0; i < 2; ++i){
    int hl = i * 32 + h2;       // 0..63
    float a = tile[4*d+0][hl] * PSCALE;
    float b = tile[4*d+1][hl] * PSCALE;
    float c = tile[4*d+2][hl] * PSCALE;
    float e = tile[4*d+3][hl] * PSCALE;
    int r = __builtin_amdgcn_cvt_pk_fp8_f32(a, b, 0, false);
    r     = __builtin_amdgcn_cvt_pk_fp8_f32(c, e, r, true);
    ws[off + (hw0 + hl) * 8 + d] = (uint32_t)r;   // coalesced 256B/wave
  }
}

// ---- geometry: 1 thread/point, writes 13 grid-space records [m][NP] ----
__global__ __launch_bounds__(256) void wpf_geom(
    const float* __restrict__ pts, const float* __restrict__ tim,
    const float* __restrict__ cov6, float4* __restrict__ rec)
{
  int pt = blockIdx.x * 256 + threadIdx.x;
  if (pt >= NP) return;

  float px = pts[pt*3+0], py = pts[pt*3+1], pz = pts[pt*3+2];
  float c00 = cov6[pt*6+0], c01 = cov6[pt*6+1], c02 = cov6[pt*6+2];
  float c11 = cov6[pt*6+3], c12 = cov6[pt*6+4], c22 = cov6[pt*6+5];

  // analytic symmetric 3x3 eigendecomposition, ascending eigenvalues
  float q3 = (c00 + c11 + c22) * (1.0f/3.0f);
  float p1 = c01*c01 + c02*c02 + c12*c12;
  float d00 = c00 - q3, d11 = c11 - q3, d22 = c22 - q3;
  float p2 = d00*d00 + d11*d11 + d22*d22 + 2.0f*p1;
  float pp = sqrtf(p2 * (1.0f/6.0f)) + 1e-30f;
  float pinv = 1.0f / pp;
  float b00 = d00*pinv, b11 = d11*pinv, b22 = d22*pinv;
  float b01 = c01*pinv, b02 = c02*pinv, b12 = c12*pinv;
  float detB = b00*(b11*b22 - b12*b12) - b01*(b01*b22 - b12*b02) + b02*(b01*b12 - b11*b02);
  float r = fminf(1.0f, fmaxf(-1.0f, 0.5f * detB));
  float phi = acosf(r) * (1.0f/3.0f);
  float l2 = q3 + 2.0f*pp*cosf(phi);                          // largest
  float l0 = q3 + 2.0f*pp*cosf(phi + 2.0943951023931953f);    // smallest
  float3 v0 = eigvec3(c00,c01,c02,c11,c12,c22, l0);
  float3 v2 = eigvec3(c00,c01,c02,c11,c12,c22, l2);
  float v1x = v2.y*v0.z - v2.z*v0.y;
  float v1y = v2.z*v0.x - v2.x*v0.z;
  float v1z = v2.x*v0.y - v2.y*v0.x;
  float v1inv = 1.0f / sqrtf(v1x*v1x + v1y*v1y + v1z*v1z + 1e-45f);
  v1x *= v1inv; v1y *= v1inv; v1z *= v1inv;

  float nx[3] = { v0.x, v0.y, v0.z };
  float ny[3] = { v1x,  v1y,  v1z  };
  float nz[3] = { v2.x, v2.y, v2.z };

  // Cinv via adjugate/det
  float A00 = c11*c22 - c12*c12;
  float A01 = c02*c12 - c01*c22;
  float A02 = c01*c12 - c02*c11;
  float A11 = c00*c22 - c02*c02;
  float A12 = c01*c02 - c00*c12;
  float A22 = c00*c11 - c01*c01;
  float det  = c00*A00 + c01*A01 + c02*A02;
  float dinv = 1.0f / det;
  float i00 = A00*dinv, i01 = A01*dinv, i02 = A02*dinv;
  float i11 = A11*dinv, i12 = A12*dinv, i22 = A22*dinv;

  // grid-space center and scaled offsets: grid = 63.5 - 39.6875*world
  float gpx = fmaf(px, -39.6875f, 63.5f);
  float gpy = fmaf(py, -39.6875f, 63.5f);
  float gpz = fmaf(pz, -39.6875f, 63.5f);
  float axA[3], ayA[3], azA[3], axB[3], ayB[3], azB[3];
  #pragma unroll
  for (int k = 0; k < 3; ++k){
    float a = nx[k], b = ny[k], c = nz[k];
    float lam = i00*a*a + i11*b*b + i22*c*c + 2.0f*(i01*a*b + i02*a*c + i12*b*c);
    float linv = 1.0f / lam;
    float sA = -39.6875f * sqrtf(KA * linv);
    float sB = -39.6875f * sqrtf(KB * linv);
    axA[k] = sA*a; ayA[k] = sA*b; azA[k] = sA*c;
    axB[k] = sB*a; ayB[k] = sB*b; azB[k] = sB*c;
  }

  // faithful to jnp.tile(t,(13,1)): sample m of point n uses time[(13n+m) % N]
  int tb = (pt * 13) % NP;
  int ti = tb;
  rec[0*NP + pt] = make_float4(gpx, gpy, gpz, tim[ti] * 99.0f);
  #pragma unroll
  for (int k = 0; k < 3; ++k){
    ti = tb + 1 + k; if (ti >= NP) ti -= NP;
    rec[(1+k)*NP + pt]  = make_float4(gpx+axA[k], gpy+ayA[k], gpz+azA[k], tim[ti]*99.0f);
  }
  #pragma unroll
  for (int k = 0; k < 3; ++k){
    ti = tb + 4 + k; if (ti >= NP) ti -= NP;
    rec[(4+k)*NP + pt]  = make_float4(gpx+axB[k], gpy+ayB[k], gpz+azB[k], tim[ti]*99.0f);
  }
  #pragma unroll
  for (int k = 0; k < 3; ++k){
    ti = tb + 7 + k; if (ti >= NP) ti -= NP;
    rec[(7+k)*NP + pt]  = make_float4(gpx-axA[k], gpy-ayA[k], gpz-azA[k], tim[ti]*99.0f);
  }
  #pragma unroll
  for (int k = 0; k < 3; ++k){
    ti = tb + 10 + k; if (ti >= NP) ti -= NP;
    rec[(10+k)*NP + pt] = make_float4(gpx-axB[k], gpy-ayB[k], gpz-azB[k], tim[ti]*99.0f);
  }
}

// ---- gather: 4 lanes/point, no LDS, no sync.
// __launch_bounds__(256,4): 128-VGPR cap. (256,8) capped at 64 VGPR and spilled
// acc[6][8] to scratch -> 1.2 GB HBM traffic, 3x slowdown (R10). Do not tighten.
__global__ __launch_bounds__(256, 4) void wpf_gather(
    const float4* __restrict__ rec, const uint32_t* __restrict__ ws,
    float* __restrict__ out)
{
  int tid = blockIdx.x * 256 + threadIdx.x;
  int pt = tid >> 2, fp = tid & 3;
  if (pt >= NP) return;
  bool xhi = (fp & 2) != 0;            // lanes 2,3 hold the x1 corner

  const uint4* __restrict__ w0p = reinterpret_cast<const uint4*>(ws + OFF0);
  const uint4* __restrict__ w1p = reinterpret_cast<const uint4*>(ws + OFF1);
  const uint4* __restrict__ w2p = reinterpret_cast<const uint4*>(ws + OFF2);
  const uint4* __restrict__ w3p = reinterpret_cast<const uint4*>(ws + OFF3);
  const uint4* __restrict__ w4p = reinterpret_cast<const uint4*>(ws + OFF4);
  const uint4* __restrict__ w5p = reinterpret_cast<const uint4*>(ws + OFF5);

  __half2 acc[6][8];                   // 16 feats/lane (this lane's x-corner partial)
  __half2 z = __float2half2_rn(0.0f);
  #pragma unroll
  for (int i = 0; i < 6; ++i)
    #pragma unroll
    for (int j = 0; j < 8; ++j) acc[i][j] = z;

  #pragma unroll 2
  for (int m = 0; m < 13; ++m){
    float4 s = rec[m*NP + pt];         // quad-broadcast 16B load
    Dim d0 = mkdim(s.x, 127);
    Dim d1 = mkdim(s.y, 127);
    Dim d2 = mkdim(s.z, 127);
    Dim dt = mkdim(s.w, 99);

    // x-use weights: zero the x1 weight when corners clamp to the same cell
    float f0x = (d0.i0 == d0.i1) ? 0.0f : d0.fr;
    float f1x = (d1.i0 == d1.i1) ? 0.0f : d1.fr;
    float ftx = (dt.i0 == dt.i1) ? 0.0f : dt.fr;

    __half2 f0h = __float2half2_rn(d0.fr), g0h = __float2half2_rn(1.0f - d0.fr);
    __half2 f1h = __float2half2_rn(d1.fr), g1h = __float2half2_rn(1.0f - d1.fr);
    __half2 f2h = __float2half2_rn(d2.fr), g2h = __float2half2_rn(1.0f - d2.fr);

    __half2 wx0 = __float2half2_rn(xhi ? f0x : 1.0f - f0x);
    __half2 wx1 = __float2half2_rn(xhi ? f1x : 1.0f - f1x);
    __half2 wxt = __float2half2_rn(xhi ? ftx : 1.0f - ftx);

    int r1a = d1.i0 << 7, r1b = d1.i1 << 7;   // y=s1, W=128 (plane0)
    int r2a = d2.i0 << 7, r2b = d2.i1 << 7;   // y=s2, W=128 (planes1,3)
    int q0a = d0.i0 * 100, q0b = d0.i1 * 100; // y=s0, W=100 (plane2)
    int q1a = d1.i0 * 100, q1b = d1.i1 * 100; // y=s1, W=100 (plane4)
    int q2a = d2.i0 * 100, q2b = d2.i1 * 100; // y=s2, W=100 (plane5)

    bilinpair(w0p, r1a, r1b, d0.i0, wx0, g1h, f1h, fp, acc[0]); // x=s0,y=s1
    bilinpair(w1p, r2a, r2b, d0.i0, wx0, g2h, f2h, fp, acc[1]); // x=s0,y=s2
    bilinpair(w2p, q0a, q0b, dt.i0, wxt, g0h, f0h, fp, acc[2]); // x=t, y=s0
    bilinpair(w3p, r2a, r2b, d1.i0, wx1, g2h, f2h, fp, acc[3]); // x=s1,y=s2
    bilinpair(w4p, q1a, q1b, dt.i0, wxt, g1h, f1h, fp, acc[4]); // x=t, y=s1
    bilinpair(w5p, q2a, q2b, dt.i0, wxt, g2h, f2h, fp, acc[5]); // x=t, y=s2
  }

  // combine x0/x1 partials across lane^2
  #pragma unroll
  for (int i = 0; i < 6; ++i)
    #pragma unroll
    for (int j = 0; j < 8; ++j){
      int o = __shfl_xor(__builtin_bit_cast(int, acc[i][j]), 2);
      acc[i][j] = __hadd2(acc[i][j], __builtin_bit_cast(__half2, o));
    }

  if (fp < 2){   // lanes 0,1 write feats 0-15 / 16-31 (lanes 2,3 are duplicates)
    const float s13 = 1.0f / (13.0f * PSCALE);
    float sp[16], st[16];
    #pragma unroll
    for (int j = 0; j < 8; ++j){
      float2 a0 = __half22float2(acc[0][j]);
      float2 a1 = __half22float2(acc[1][j]);
      float2 a2 = __half22float2(acc[2][j]);
      float2 a3 = __half22float2(acc[3][j]);
      float2 a4 = __half22float2(acc[4][j]);
      float2 a5 = __half22float2(acc[5][j]);
      sp[2*j]   = (a0.x*s13)*(a1.x*s13)*(a3.x*s13);
      sp[2*j+1] = (a0.y*s13)*(a1.y*s13)*(a3.y*s13);
      st[2*j]   = (a2.x*s13)*(a4.x*s13)*(a5.x*s13);
      st[2*j+1] = (a2.y*s13)*(a4.y*s13)*(a5.y*s13);
    }
    float* osp = out + pt*32 + fp*16;
    float* ost = osp + NP*32;
    #pragma unroll
    for (int q = 0; q < 4; ++q){
      reinterpret_cast<float4*>(osp)[q] = make_float4(sp[4*q], sp[4*q+1], sp[4*q+2], sp[4*q+3]);
      reinterpret_cast<float4*>(ost)[q] = make_float4(st[4*q], st[4*q+1], st[4*q+2], st[4*q+3]);
    }
  }
}

extern "C" void kernel_launch(void* const* d_in, const int* in_sizes, int n_in,
                              void* d_out, int out_size, void* d_ws, size_t ws_size,
                              hipStream_t stream) {
  (void)in_sizes; (void)n_in; (void)out_size; (void)ws_size;
  const float* pts  = (const float*)d_in[0];
  const float* tim  = (const float*)d_in[1];
  const float* cov6 = (const float*)d_in[2];
  const float* p0 = (const float*)d_in[3];
  const float* p1 = (const float*)d_in[4];
  const float* p2 = (const float*)d_in[5];
  const float* p3 = (const float*)d_in[6];
  const float* p4 = (const float*)d_in[7];
  const float* p5 = (const float*)d_in[8];
  float* out = (float*)d_out;
  uint32_t* ws = (uint32_t*)d_ws;
  float4* rec = reinterpret_cast<float4*>(ws + REC_OFF);

  dim3 tgrid(256, 6);
  wpf_transpose<<<tgrid, 256, 0, stream>>>(p0, p1, p2, p3, p4, p5, ws, out + 2*NP*32);

  wpf_geom<<<(NP + 255) / 256, 256, 0, stream>>>(pts, tim, cov6, rec);

  int nthreads = NP * 4;
  wpf_gather<<<(nthreads + 255) / 256, 256, 0, stream>>>(rec, ws, out);
}

// Round 13
// 172.745 us; speedup vs baseline: 2.1344x; 1.0968x over previous
//
#include <hip/hip_runtime.h>
#include <hip/hip_fp16.h>
#include <stdint.h>

#define NP 100000
#define PPB 32            // points per block (8 lanes/point * 32 = 256 threads)
#define KA 3.2188758248682006f   // -2*ln(0.2)
#define KB 0.44628710262841953f  // -2*ln(0.8)
#define PSCALE 16.0f             // planes stored *16 in e4m3; folded out at epilogue

// workspace layout in DWORDS: planes as [H][W][8 dwords] fp8 (32 feats * 1B)
#define SS_DW 131072    // 128*128*8
#define ST_DW 102400    // 128*100*8
#define OFF0 0
#define OFF1 (OFF0 + SS_DW)
#define OFF2 (OFF1 + SS_DW)
#define OFF3 (OFF2 + ST_DW)
#define OFF4 (OFF3 + SS_DW)
#define OFF5 (OFF4 + ST_DW)

typedef float v2f __attribute__((ext_vector_type(2)));
typedef __fp16 v2h __attribute__((ext_vector_type(2)));

__device__ __forceinline__ int clampi(int v, int hi){ v = v < 0 ? 0 : v; return v > hi ? hi : v; }

struct Dim { int i0, i1; float fr; };

__device__ __forceinline__ Dim mkdim(float g, int hi){
  float fl = floorf(g);
  Dim d;
  d.fr = g - fl;            // unclipped fractional weight (faithful to reference)
  int i = (int)fl;
  d.i0 = clampi(i, hi);
  d.i1 = clampi(i + 1, hi);
  return d;
}

// decode 2 fp8 -> 2 f16 (direct HW path when available; else via f32).
template<bool HI>
__device__ __forceinline__ __half2 dec8(uint32_t w){
#if __has_builtin(__builtin_amdgcn_cvt_scalef32_pk_f16_fp8)
  v2h h = __builtin_amdgcn_cvt_scalef32_pk_f16_fp8(w, 1.0f, HI);
  return __builtin_bit_cast(__half2, h);
#else
  v2f f = __builtin_amdgcn_cvt_pk_f32_fp8((int)w, HI);
  v2h h = __builtin_amdgcn_cvt_pkrtz(f.x, f.y);
  return __builtin_bit_cast(__half2, h);
#endif
}

// decode 16 fp8 feats (uint4) and accumulate with packed-f16 weight
__device__ __forceinline__ void row8(uint4 v, __half2 w, __half2* acc){
  acc[0] = __hfma2(dec8<false>(v.x), w, acc[0]);
  acc[1] = __hfma2(dec8<true >(v.x), w, acc[1]);
  acc[2] = __hfma2(dec8<false>(v.y), w, acc[2]);
  acc[3] = __hfma2(dec8<true >(v.y), w, acc[3]);
  acc[4] = __hfma2(dec8<false>(v.z), w, acc[4]);
  acc[5] = __hfma2(dec8<true >(v.z), w, acc[5]);
  acc[6] = __hfma2(dec8<false>(v.w), w, acc[6]);
  acc[7] = __hfma2(dec8<true >(v.w), w, acc[7]);
}

__device__ __forceinline__ float3 eigvec3(float c00,float c01,float c02,
                                          float c11,float c12,float c22,float lam){
  float m00 = c00 - lam, m11 = c11 - lam, m22 = c22 - lam;
  float ux0 = c01*c12 - c02*m11, uy0 = c02*c01 - m00*c12, uz0 = m00*m11 - c01*c01;
  float ux1 = c01*m22 - c02*c12, uy1 = c02*c02 - m00*m22, uz1 = m00*c12 - c01*c02;
  float ux2 = m11*m22 - c12*c12, uy2 = c12*c02 - c01*m22, uz2 = c01*c12 - m11*c02;
  float n0 = ux0*ux0 + uy0*uy0 + uz0*uz0;
  float n1 = ux1*ux1 + uy1*uy1 + uz1*uz1;
  float n2 = ux2*ux2 + uy2*uy2 + uz2*uz2;
  float ux = ux0, uy = uy0, uz = uz0, nn = n0;
  if (n1 > nn){ ux = ux1; uy = uy1; uz = uz1; nn = n1; }
  if (n2 > nn){ ux = ux2; uy = uy2; uz = uz2; nn = n2; }
  float inv = 1.0f / sqrtf(nn + 1e-45f);
  return make_float3(ux*inv, uy*inv, uz*inv);
}

// ---- transpose + quantize: [32][HW] f32 -> [HW][32] fp8 (*16), coalesced ----
__global__ __launch_bounds__(256) void wpf_transpose(
    const float* __restrict__ p0, const float* __restrict__ p1,
    const float* __restrict__ p2, const float* __restrict__ p3,
    const float* __restrict__ p4, const float* __restrict__ p5,
    uint32_t* __restrict__ ws, float* __restrict__ coltime)
{
  __shared__ float tile[32][65];
  int plane = blockIdx.y;
  if (plane == 0 && blockIdx.x == 0 && threadIdx.x == 0) coltime[0] = 1.0f;
  const float* src; int off, HW;
  switch (plane){
    case 0:  src = p0; off = OFF0; HW = 16384; break;
    case 1:  src = p1; off = OFF1; HW = 16384; break;
    case 2:  src = p2; off = OFF2; HW = 12800; break;
    case 3:  src = p3; off = OFF3; HW = 16384; break;
    case 4:  src = p4; off = OFF4; HW = 12800; break;
    default: src = p5; off = OFF5; HW = 12800; break;
  }
  int hw0 = blockIdx.x * 64;
  if (hw0 >= HW) return;
  int hwt = threadIdx.x & 63;
  int fq  = threadIdx.x >> 6;   // 0..3
  #pragma unroll
  for (int i = 0; i < 8; ++i){
    int f = fq * 8 + i;         // 0..31
    tile[f][hwt] = src[f * HW + hw0 + hwt];  // coalesced
  }
  __syncthreads();
  int d  = threadIdx.x & 7;     // dword index 0..7 (feats 4d..4d+3)
  int h2 = threadIdx.x >> 3;    // 0..31
  #pragma unroll
  for (int i = 0; i < 2; ++i){
    int hl = i * 32 + h2;       // 0..63
    float a = tile[4*d+0][hl] * PSCALE;
    float b = tile[4*d+1][hl] * PSCALE;
    float c = tile[4*d+2][hl] * PSCALE;
    float e = tile[4*d+3][hl] * PSCALE;
    int r = __builtin_amdgcn_cvt_pk_fp8_f32(a, b, 0, false);
    r     = __builtin_amdgcn_cvt_pk_fp8_f32(c, e, r, true);
    ws[off + (hw0 + hl) * 8 + d] = (uint32_t)r;   // coalesced 256B/wave
  }
}

// ---- fused main: phase1 geometry (32 threads) -> LDS, phase2 gather (8 lanes/pt).
// 8 lanes/point: fp&2 selects x-corner, fp&4 selects y-row -> 1 load per
// plane-sample per lane (78 total vs 156 at 4 lanes/pt); combine via
// shfl_xor(2) then shfl_xor(4).
// __launch_bounds__(256,4): (256,8) caps VGPR at 64 and spills acc to scratch
// -> 1.2 GB HBM traffic, 3x slowdown (R10). Do not tighten.
__global__ __launch_bounds__(256, 4) void wpf_main(
    const float* __restrict__ pts, const float* __restrict__ tim,
    const float* __restrict__ cov6, const uint32_t* __restrict__ ws,
    float* __restrict__ out)
{
  __shared__ float4 smp[PPB][13];   // grid-space (gx,gy,gz,gt) per sample
  int tidl = threadIdx.x;
  int pbase = blockIdx.x * PPB;

  if (tidl < PPB){
    int pt = pbase + tidl;
    float px = pts[pt*3+0], py = pts[pt*3+1], pz = pts[pt*3+2];
    float c00 = cov6[pt*6+0], c01 = cov6[pt*6+1], c02 = cov6[pt*6+2];
    float c11 = cov6[pt*6+3], c12 = cov6[pt*6+4], c22 = cov6[pt*6+5];

    // analytic symmetric 3x3 eigendecomposition, ascending eigenvalues
    float q3 = (c00 + c11 + c22) * (1.0f/3.0f);
    float p1 = c01*c01 + c02*c02 + c12*c12;
    float d00 = c00 - q3, d11 = c11 - q3, d22 = c22 - q3;
    float p2 = d00*d00 + d11*d11 + d22*d22 + 2.0f*p1;
    float pp = sqrtf(p2 * (1.0f/6.0f)) + 1e-30f;
    float pinv = 1.0f / pp;
    float b00 = d00*pinv, b11 = d11*pinv, b22 = d22*pinv;
    float b01 = c01*pinv, b02 = c02*pinv, b12 = c12*pinv;
    float detB = b00*(b11*b22 - b12*b12) - b01*(b01*b22 - b12*b02) + b02*(b01*b12 - b11*b02);
    float r = fminf(1.0f, fmaxf(-1.0f, 0.5f * detB));
    float phi = acosf(r) * (1.0f/3.0f);
    float l2 = q3 + 2.0f*pp*cosf(phi);                          // largest
    float l0 = q3 + 2.0f*pp*cosf(phi + 2.0943951023931953f);    // smallest
    float3 v0 = eigvec3(c00,c01,c02,c11,c12,c22, l0);
    float3 v2 = eigvec3(c00,c01,c02,c11,c12,c22, l2);
    float v1x = v2.y*v0.z - v2.z*v0.y;
    float v1y = v2.z*v0.x - v2.x*v0.z;
    float v1z = v2.x*v0.y - v2.y*v0.x;
    float v1inv = 1.0f / sqrtf(v1x*v1x + v1y*v1y + v1z*v1z + 1e-45f);
    v1x *= v1inv; v1y *= v1inv; v1z *= v1inv;

    // normals = rows of V (V columns v0,v1,v2): n_k = (v0[k], v1[k], v2[k])
    float nx[3] = { v0.x, v0.y, v0.z };
    float ny[3] = { v1x,  v1y,  v1z  };
    float nz[3] = { v2.x, v2.y, v2.z };

    // Cinv via adjugate/det
    float A00 = c11*c22 - c12*c12;
    float A01 = c02*c12 - c01*c22;
    float A02 = c01*c12 - c02*c11;
    float A11 = c00*c22 - c02*c02;
    float A12 = c01*c02 - c00*c12;
    float A22 = c00*c11 - c01*c01;
    float det  = c00*A00 + c01*A01 + c02*A02;
    float dinv = 1.0f / det;
    float i00 = A00*dinv, i01 = A01*dinv, i02 = A02*dinv;
    float i11 = A11*dinv, i12 = A12*dinv, i22 = A22*dinv;

    // grid-space center and scaled offsets: grid = 63.5 - 39.6875*world
    float gpx = fmaf(px, -39.6875f, 63.5f);
    float gpy = fmaf(py, -39.6875f, 63.5f);
    float gpz = fmaf(pz, -39.6875f, 63.5f);
    float axA[3], ayA[3], azA[3], axB[3], ayB[3], azB[3];
    #pragma unroll
    for (int k = 0; k < 3; ++k){
      float a = nx[k], b = ny[k], c = nz[k];
      float lam = i00*a*a + i11*b*b + i22*c*c + 2.0f*(i01*a*b + i02*a*c + i12*b*c);
      float linv = 1.0f / lam;
      float sA = -39.6875f * sqrtf(KA * linv);
      float sB = -39.6875f * sqrtf(KB * linv);
      axA[k] = sA*a; ayA[k] = sA*b; azA[k] = sA*c;
      axB[k] = sB*a; ayB[k] = sB*b; azB[k] = sB*c;
    }

    // faithful to jnp.tile(t,(13,1)): sample m of point n uses time[(13n+m) % N]
    int tb = (pt * 13) % NP;
    int ti = tb;
    smp[tidl][0] = make_float4(gpx, gpy, gpz, tim[ti] * 99.0f);
    #pragma unroll
    for (int k = 0; k < 3; ++k){
      ti = tb + 1 + k; if (ti >= NP) ti -= NP;
      smp[tidl][1+k]  = make_float4(gpx+axA[k], gpy+ayA[k], gpz+azA[k], tim[ti]*99.0f);
    }
    #pragma unroll
    for (int k = 0; k < 3; ++k){
      ti = tb + 4 + k; if (ti >= NP) ti -= NP;
      smp[tidl][4+k]  = make_float4(gpx+axB[k], gpy+ayB[k], gpz+azB[k], tim[ti]*99.0f);
    }
    #pragma unroll
    for (int k = 0; k < 3; ++k){
      ti = tb + 7 + k; if (ti >= NP) ti -= NP;
      smp[tidl][7+k]  = make_float4(gpx-axA[k], gpy-ayA[k], gpz-azA[k], tim[ti]*99.0f);
    }
    #pragma unroll
    for (int k = 0; k < 3; ++k){
      ti = tb + 10 + k; if (ti >= NP) ti -= NP;
      smp[tidl][10+k] = make_float4(gpx-axB[k], gpy-ayB[k], gpz-azB[k], tim[ti]*99.0f);
    }
  }
  __syncthreads();

  int lp = tidl >> 3, fp = tidl & 7;   // 8 lanes/point
  int pt = pbase + lp;                 // NP % PPB == 0: no tail
  bool xhi = (fp & 2) != 0;            // x-corner select
  bool yhi = (fp & 4) != 0;            // y-row select
  int q = fp & 3;                      // uint4 index within the 64B (x0,x1) span

  const uint4* __restrict__ w0p = reinterpret_cast<const uint4*>(ws + OFF0);
  const uint4* __restrict__ w1p = reinterpret_cast<const uint4*>(ws + OFF1);
  const uint4* __restrict__ w2p = reinterpret_cast<const uint4*>(ws + OFF2);
  const uint4* __restrict__ w3p = reinterpret_cast<const uint4*>(ws + OFF3);
  const uint4* __restrict__ w4p = reinterpret_cast<const uint4*>(ws + OFF4);
  const uint4* __restrict__ w5p = reinterpret_cast<const uint4*>(ws + OFF5);

  __half2 acc[6][8];                   // 16 feats/lane (this lane's (x,y)-corner partial)
  __half2 z = __float2half2_rn(0.0f);
  #pragma unroll
  for (int i = 0; i < 6; ++i)
    #pragma unroll
    for (int j = 0; j < 8; ++j) acc[i][j] = z;

  #pragma unroll 2
  for (int m = 0; m < 13; ++m){
    float4 s = smp[lp][m];
    Dim d0 = mkdim(s.x, 127);
    Dim d1 = mkdim(s.y, 127);
    Dim d2 = mkdim(s.z, 127);
    Dim dt = mkdim(s.w, 99);

    // x-use weights: zero the x1 weight when corners clamp to the same cell
    float f0x = (d0.i0 == d0.i1) ? 0.0f : d0.fr;
    float f1x = (d1.i0 == d1.i1) ? 0.0f : d1.fr;
    float ftx = (dt.i0 == dt.i1) ? 0.0f : dt.fr;

    float wx0 = xhi ? f0x : 1.0f - f0x;
    float wx1 = xhi ? f1x : 1.0f - f1x;
    float wxt = xhi ? ftx : 1.0f - ftx;
    // y weights (clamped-equal y: both rows same, weights sum to 1 — correct)
    float wy0 = yhi ? d0.fr : 1.0f - d0.fr;
    float wy1 = yhi ? d1.fr : 1.0f - d1.fr;
    float wy2 = yhi ? d2.fr : 1.0f - d2.fr;
    // per-lane y-row indices
    int yi0 = yhi ? d0.i1 : d0.i0;
    int yi1 = yhi ? d1.i1 : d1.i0;
    int yi2 = yhi ? d2.i1 : d2.i0;

    __half2 w0 = __float2half2_rn(wx0 * wy1);   // plane0: x=s0,y=s1
    __half2 w1 = __float2half2_rn(wx0 * wy2);   // plane1: x=s0,y=s2
    __half2 w2 = __float2half2_rn(wxt * wy0);   // plane2: x=t, y=s0
    __half2 w3 = __float2half2_rn(wx1 * wy2);   // plane3: x=s1,y=s2
    __half2 w4 = __float2half2_rn(wxt * wy1);   // plane4: x=t, y=s1
    __half2 w5 = __float2half2_rn(wxt * wy2);   // plane5: x=t, y=s2

    row8(w0p[(((yi1 << 7) + d0.i0) << 1) + q], w0, acc[0]);
    row8(w1p[(((yi2 << 7) + d0.i0) << 1) + q], w1, acc[1]);
    row8(w2p[(((yi0 * 100) + dt.i0) << 1) + q], w2, acc[2]);
    row8(w3p[(((yi2 << 7) + d1.i0) << 1) + q], w3, acc[3]);
    row8(w4p[(((yi1 * 100) + dt.i0) << 1) + q], w4, acc[4]);
    row8(w5p[(((yi2 * 100) + dt.i0) << 1) + q], w5, acc[5]);
  }

  // combine x0/x1 partials (lane^2), then y0/y1 partials (lane^4)
  #pragma unroll
  for (int i = 0; i < 6; ++i)
    #pragma unroll
    for (int j = 0; j < 8; ++j){
      int o = __shfl_xor(__builtin_bit_cast(int, acc[i][j]), 2);
      acc[i][j] = __hadd2(acc[i][j], __builtin_bit_cast(__half2, o));
    }
  #pragma unroll
  for (int i = 0; i < 6; ++i)
    #pragma unroll
    for (int j = 0; j < 8; ++j){
      int o = __shfl_xor(__builtin_bit_cast(int, acc[i][j]), 4);
      acc[i][j] = __hadd2(acc[i][j], __builtin_bit_cast(__half2, o));
    }

  if (fp < 2){   // lanes 0,1 of each octet write feats 0-15 / 16-31
    const float s13 = 1.0f / (13.0f * PSCALE);
    float sp[16], st[16];
    #pragma unroll
    for (int j = 0; j < 8; ++j){
      float2 a0 = __half22float2(acc[0][j]);
      float2 a1 = __half22float2(acc[1][j]);
      float2 a2 = __half22float2(acc[2][j]);
      float2 a3 = __half22float2(acc[3][j]);
      float2 a4 = __half22float2(acc[4][j]);
      float2 a5 = __half22float2(acc[5][j]);
      sp[2*j]   = (a0.x*s13)*(a1.x*s13)*(a3.x*s13);
      sp[2*j+1] = (a0.y*s13)*(a1.y*s13)*(a3.y*s13);
      st[2*j]   = (a2.x*s13)*(a4.x*s13)*(a5.x*s13);
      st[2*j+1] = (a2.y*s13)*(a4.y*s13)*(a5.y*s13);
    }
    float* osp = out + pt*32 + fp*16;
    float* ost = osp + NP*32;
    #pragma unroll
    for (int qq = 0; qq < 4; ++qq){
      reinterpret_cast<float4*>(osp)[qq] = make_float4(sp[4*qq], sp[4*qq+1], sp[4*qq+2], sp[4*qq+3]);
      reinterpret_cast<float4*>(ost)[qq] = make_float4(st[4*qq], st[4*qq+1], st[4*qq+2], st[4*qq+3]);
    }
  }
}

extern "C" void kernel_launch(void* const* d_in, const int* in_sizes, int n_in,
                              void* d_out, int out_size, void* d_ws, size_t ws_size,
                              hipStream_t stream) {
  (void)in_sizes; (void)n_in; (void)out_size; (void)ws_size;
  const float* pts  = (const float*)d_in[0];
  const float* tim  = (const float*)d_in[1];
  const float* cov6 = (const float*)d_in[2];
  const float* p0 = (const float*)d_in[3];
  const float* p1 = (const float*)d_in[4];
  const float* p2 = (const float*)d_in[5];
  const float* p3 = (const float*)d_in[6];
  const float* p4 = (const float*)d_in[7];
  const float* p5 = (const float*)d_in[8];
  float* out = (float*)d_out;
  uint32_t* ws = (uint32_t*)d_ws;

  dim3 tgrid(256, 6);
  wpf_transpose<<<tgrid, 256, 0, stream>>>(p0, p1, p2, p3, p4, p5, ws, out + 2*NP*32);

  wpf_main<<<NP / PPB, 256, 0, stream>>>(pts, tim, cov6, ws, out);   // 3125 blocks
}